// Round 1
// 752.534 us; speedup vs baseline: 2.3429x; 2.3429x over previous
//
#include <hip/hip_runtime.h>
#include <hip/hip_bf16.h>

#define NTOK 49
#define DIM  256
#define NH   8
#define DH   32
#define NB   2048

// ---------- MFMA fragment types (per guide §3: 8 bf16 in 4 VGPRs as short8) ----------
typedef __attribute__((ext_vector_type(8))) short bf16x8;
typedef __attribute__((ext_vector_type(4))) float f32x4;

// ---------- bf16 split helpers (RNE, finite inputs only) ----------
__device__ __forceinline__ unsigned short f2bf(float f) {
  unsigned int u = __float_as_uint(f);
  return (unsigned short)((u + 0x7FFFu + ((u >> 16) & 1u)) >> 16);
}
__device__ __forceinline__ float bf2f(unsigned short h) {
  return __uint_as_float(((unsigned int)h) << 16);
}
__device__ __forceinline__ void split8(const float v[8], bf16x8& hv, bf16x8& lv) {
#pragma unroll
  for (int t = 0; t < 8; ++t) {
    unsigned short hb = f2bf(v[t]);
    hv[t] = (short)hb;
    lv[t] = (short)f2bf(v[t] - bf2f(hb));
  }
}

// ---------- dtype-polymorphic load/store ----------
__device__ __forceinline__ float ldf(const float* p, size_t i) { return p[i]; }
__device__ __forceinline__ float ldf(const __hip_bfloat16* p, size_t i) { return __bfloat162float(p[i]); }
__device__ __forceinline__ void stf(float* p, size_t i, float v) { p[i] = v; }
__device__ __forceinline__ void stf(__hip_bfloat16* p, size_t i, float v) { p[i] = __float2bfloat16(v); }

// ---------- dtype detector ----------
__global__ void dtype_detect_kernel(const unsigned int* __restrict__ x, int* flag) {
  if (blockIdx.x == 0 && threadIdx.x == 0) {
    int hits = 0;
    for (int i = 0; i < 64; ++i) {
      unsigned int lo = x[i] & 0xFFFFu;
      unsigned int e = (lo >> 7) & 0xFFu;
      if (e >= 110u && e <= 140u) hits++;
    }
    *flag = (hits >= 32) ? 1 : 0;   // 1 = bf16, 0 = fp32
  }
}

// ---------- workspace layout (ushorts, after 16-byte flag slot) ----------
#define OFF_QH 0
#define OFF_QL 196608
#define OFF_PH 393216
#define OFF_PL 458752
// total 524288 ushorts = 1,048,576 bytes

// ---------- prep: split weights into bf16 hi/lo in workspace ----------
template <typename T>
__global__ void prep_w_kernel(const T* __restrict__ qkv_w, const T* __restrict__ proj_w,
                              unsigned short* __restrict__ wsb,
                              const int* __restrict__ flag, int want) {
  if (*flag != want) return;
  int idx = blockIdx.x * blockDim.x + threadIdx.x;
  int stride = gridDim.x * blockDim.x;
  for (int i = idx; i < 768 * 256; i += stride) {
    float v = ldf(qkv_w, (size_t)i);
    unsigned short hb = f2bf(v);
    wsb[OFF_QH + i] = hb;
    wsb[OFF_QL + i] = f2bf(v - bf2f(hb));
  }
  for (int i = idx; i < 256 * 256; i += stride) {
    float v = ldf(proj_w, (size_t)i);
    unsigned short hb = f2bf(v);
    wsb[OFF_PH + i] = hb;
    wsb[OFF_PL + i] = f2bf(v - bf2f(hb));
  }
}

// ---------- MFMA fused QKV + window attention ----------
// Block = (window b, head h), 256 threads / 4 waves.
// QKV GEMM: M=64 (49 padded), N=96, K=256, K-tile=64, mfma_f32_16x16x32_bf16.
// fp32 path: bf16x3 split (hi*hi + hi*lo + lo*hi), error ~1e-4 absolute.
// LDS: staging (x hi/lo [64][72] + w hi/lo [96][72] ushort) UNION attn arrays
//      (q/k/v [49][36] f32 + scores [49][52] f32) -> 46080 B -> 3 blocks/CU.
template <typename T>
__global__ __launch_bounds__(256, 3)
void win_attn_mfma_kernel(const T* __restrict__ x, const T* __restrict__ maskp,
                          const T* __restrict__ qkv_b,
                          const T* __restrict__ rpb_table, const int* __restrict__ rel_index,
                          const unsigned short* __restrict__ wsb,
                          T* __restrict__ out, const int* __restrict__ flag, int want)
{
  if (*flag != want) return;
  constexpr int NS = (sizeof(T) == 4) ? 2 : 1;          // 2 = hi+lo split, 1 = hi only
  constexpr int SMEM_BYTES = (NS == 2) ? 46080 : 31360; // max(stage, attn)
  __shared__ __align__(16) char smem[SMEM_BYTES];

  unsigned short* xh = (unsigned short*)smem;           // [64][72]
  unsigned short* xl = xh + 64 * 72;                    // [64][72] (NS==2 only)
  unsigned short* wh = xh + NS * 64 * 72;               // [96][72]
  unsigned short* wl = wh + 96 * 72;                    // [96][72] (NS==2 only)
  float* qs  = (float*)smem;                            // [49][36] (q, pre-scaled)
  float* ksb = qs  + NTOK * 36;                         // [49][36]
  float* vsb = ksb + NTOK * 36;                         // [49][36]
  float* smx = vsb + NTOK * 36;                         // [49][52] scores/probs

  const int b = blockIdx.x, h = blockIdx.y;
  const int tid = threadIdx.x;
  const int lane = tid & 63, wid = tid >> 6;
  const int wrow = (wid & 1) * 32, wcol = (wid >> 1) * 48;  // wave tile 32x48
  const int l15 = lane & 15, l4 = lane >> 4;
  const float SCALE = 0.17677669529663687f;             // 32^-0.5
  const size_t xbase = (size_t)b * NTOK * DIM;
  const unsigned short* qh = wsb + OFF_QH;
  const unsigned short* ql = wsb + OFF_QL;

  f32x4 acc[2][3];
#pragma unroll
  for (int fi = 0; fi < 2; ++fi)
#pragma unroll
    for (int ni = 0; ni < 3; ++ni) acc[fi][ni] = (f32x4){0.f, 0.f, 0.f, 0.f};

  for (int kt = 0; kt < DIM; kt += 64) {
    // ---- stage x tile (rows < 49 only; padded rows are garbage, never stored) ----
    if constexpr (NS == 2) {
      const float* xf = reinterpret_cast<const float*>(x);
      for (int i = tid; i < NTOK * 16; i += 256) {
        int n = i >> 4, k4 = (i & 15) * 4;
        const float4 v = *(const float4*)(xf + xbase + n * DIM + kt + k4);
        ushort4 hh, ll;
        hh.x = f2bf(v.x); ll.x = f2bf(v.x - bf2f(hh.x));
        hh.y = f2bf(v.y); ll.y = f2bf(v.y - bf2f(hh.y));
        hh.z = f2bf(v.z); ll.z = f2bf(v.z - bf2f(hh.z));
        hh.w = f2bf(v.w); ll.w = f2bf(v.w - bf2f(hh.w));
        *(ushort4*)(xh + n * 72 + k4) = hh;
        *(ushort4*)(xl + n * 72 + k4) = ll;
      }
    } else {
      const unsigned short* xu = reinterpret_cast<const unsigned short*>(x);
      for (int i = tid; i < NTOK * 8; i += 256) {
        int n = i >> 3, k8 = (i & 7) * 8;
        *(int4*)(xh + n * 72 + k8) = *(const int4*)(xu + xbase + n * DIM + kt + k8);
      }
    }
    // ---- stage pre-split qkv_w head-slice (96 rows: c*256 + h*32 + d) ----
    for (int i = tid; i < 96 * 8; i += 256) {
      int j = i >> 3, k8 = (i & 7) * 8;
      int G = (j >> 5) * DIM + h * DH + (j & 31);
      *(int4*)(wh + j * 72 + k8) = *(const int4*)(qh + (size_t)G * DIM + kt + k8);
      if constexpr (NS == 2)
        *(int4*)(wl + j * 72 + k8) = *(const int4*)(ql + (size_t)G * DIM + kt + k8);
    }
    __syncthreads();

#pragma unroll
    for (int ks = 0; ks < 2; ++ks) {
      const int ka = ks * 32 + l4 * 8;
      bf16x8 Ah[2], Al[2], Bh[3], Bl[3];
#pragma unroll
      for (int fi = 0; fi < 2; ++fi) {
        int off = (wrow + fi * 16 + l15) * 72 + ka;
        Ah[fi] = *(const bf16x8*)(xh + off);
        if constexpr (NS == 2) Al[fi] = *(const bf16x8*)(xl + off);
      }
#pragma unroll
      for (int ni = 0; ni < 3; ++ni) {
        int off = (wcol + ni * 16 + l15) * 72 + ka;
        Bh[ni] = *(const bf16x8*)(wh + off);
        if constexpr (NS == 2) Bl[ni] = *(const bf16x8*)(wl + off);
      }
#pragma unroll
      for (int fi = 0; fi < 2; ++fi)
#pragma unroll
        for (int ni = 0; ni < 3; ++ni) {
          acc[fi][ni] = __builtin_amdgcn_mfma_f32_16x16x32_bf16(Ah[fi], Bh[ni], acc[fi][ni], 0, 0, 0);
          if constexpr (NS == 2) {
            acc[fi][ni] = __builtin_amdgcn_mfma_f32_16x16x32_bf16(Ah[fi], Bl[ni], acc[fi][ni], 0, 0, 0);
            acc[fi][ni] = __builtin_amdgcn_mfma_f32_16x16x32_bf16(Al[fi], Bh[ni], acc[fi][ni], 0, 0, 0);
          }
        }
    }
    __syncthreads();   // all frag reads done before next stage / epilogue overwrites union
  }

  // ---- epilogue: bias (+scale q), scatter into q/k/v LDS ----
  // C/D layout (m89/m91 verified): col = lane&15, row = (lane>>4)*4 + reg
#pragma unroll
  for (int fi = 0; fi < 2; ++fi) {
    int rbase = wrow + fi * 16 + l4 * 4;
#pragma unroll
    for (int ni = 0; ni < 3; ++ni) {
      int j = wcol + ni * 16 + l15;
      int c = j >> 5, d = j & 31;
      float bias = ldf(qkv_b, (size_t)(c * DIM + h * DH + d));
#pragma unroll
      for (int r = 0; r < 4; ++r) {
        int row = rbase + r;
        if (row < NTOK) {
          float val = acc[fi][ni][r] + bias;
          if (c == 0)      qs[row * 36 + d]  = val * SCALE;
          else if (c == 1) ksb[row * 36 + d] = val;
          else             vsb[row * 36 + d] = val;
        }
      }
    }
  }
  __syncthreads();

  // ---- scores: S[i][j] = q_i . k_j + rpb + mask ----
  const int w = b & 63;
  for (int e = tid; e < NTOK * NTOK; e += 256) {
    int i = e / 49, j = e % 49;
    const float4* qi = (const float4*)(qs + i * 36);
    const float4* kj = (const float4*)(ksb + j * 36);
    float s = 0.0f;
#pragma unroll
    for (int d4 = 0; d4 < 8; ++d4) {
      float4 a = qi[d4], c = kj[d4];
      s += a.x * c.x + a.y * c.y + a.z * c.z + a.w * c.w;
    }
    s += ldf(rpb_table, (size_t)rel_index[e] * NH + h);
    s += ldf(maskp, (size_t)w * NTOK * NTOK + e);
    smx[i * 52 + j] = s;
  }
  __syncthreads();

  // ---- softmax per row ----
  if (tid < NTOK) {
    int i = tid;
    float mx = -3.4e38f;
    for (int j = 0; j < NTOK; ++j) mx = fmaxf(mx, smx[i * 52 + j]);
    float sum = 0.0f;
    for (int j = 0; j < NTOK; ++j) {
      float ev = __expf(smx[i * 52 + j] - mx);
      smx[i * 52 + j] = ev;
      sum += ev;
    }
    float inv = 1.0f / sum;
    for (int j = 0; j < NTOK; ++j) smx[i * 52 + j] *= inv;
  }
  __syncthreads();

  // ---- O = P @ V (float4 over d) ----
  for (int e = tid; e < NTOK * 8; e += 256) {
    int i = e >> 3, d4 = (e & 7) * 4;
    float4 o = {0.f, 0.f, 0.f, 0.f};
    for (int j = 0; j < NTOK; ++j) {
      float p = smx[i * 52 + j];
      const float4 vv = *(const float4*)(vsb + j * 36 + d4);
      o.x += p * vv.x; o.y += p * vv.y; o.z += p * vv.z; o.w += p * vv.w;
    }
    size_t base = ((size_t)b * NTOK + i) * DIM + h * DH + d4;
    if constexpr (sizeof(T) == 4) {
      *(float4*)(reinterpret_cast<float*>(out) + base) = o;
    } else {
      stf(out, base + 0, o.x); stf(out, base + 1, o.y);
      stf(out, base + 2, o.z); stf(out, base + 3, o.w);
    }
  }
}

// ---------- MFMA in-place output projection ----------
// Block = 64 rows x full 256 cols (row-disjoint -> in-place safe; all A reads
// consumed by MFMA before epilogue stores). 4 waves: 2x2 grid, wave tile 32x128.
// A-fragments loaded directly from global (8 contiguous elems/lane) + inline split.
template <typename T>
__global__ __launch_bounds__(256, 2)
void proj_mfma_kernel(T* __restrict__ out, const unsigned short* __restrict__ wsb,
                      const T* __restrict__ proj_b, const int* __restrict__ flag, int want)
{
  if (*flag != want) return;
  constexpr int NS = (sizeof(T) == 4) ? 2 : 1;
  constexpr int SMEM_BYTES = NS * 256 * 72 * 2;   // 73728 fp32 / 36864 bf16
  __shared__ __align__(16) char smem[SMEM_BYTES];
  unsigned short* wh = (unsigned short*)smem;     // [256][72]
  unsigned short* wl = wh + 256 * 72;             // NS==2 only

  const int tid = threadIdx.x;
  const int lane = tid & 63, wid = tid >> 6;
  const int wrow = (wid & 1) * 32, wcol = (wid >> 1) * 128;
  const int l15 = lane & 15, l4 = lane >> 4;
  const size_t r0 = (size_t)blockIdx.x * 64;      // 100352 / 64 = 1568 blocks exact
  const unsigned short* ph = wsb + OFF_PH;
  const unsigned short* pl = wsb + OFF_PL;

  f32x4 acc[2][8];
#pragma unroll
  for (int fi = 0; fi < 2; ++fi)
#pragma unroll
    for (int ni = 0; ni < 8; ++ni) acc[fi][ni] = (f32x4){0.f, 0.f, 0.f, 0.f};

  for (int kt = 0; kt < DIM; kt += 64) {
    // stage pre-split proj_w k-slab (all 256 output rows)
    for (int i = tid; i < 256 * 8; i += 256) {
      int j = i >> 3, k8 = (i & 7) * 8;
      *(int4*)(wh + j * 72 + k8) = *(const int4*)(ph + (size_t)j * DIM + kt + k8);
      if constexpr (NS == 2)
        *(int4*)(wl + j * 72 + k8) = *(const int4*)(pl + (size_t)j * DIM + kt + k8);
    }
    __syncthreads();

#pragma unroll
    for (int ks = 0; ks < 2; ++ks) {
      const int koff = kt + ks * 32 + l4 * 8;
      bf16x8 Ah[2], Al[2];
#pragma unroll
      for (int fi = 0; fi < 2; ++fi) {
        size_t row = r0 + wrow + fi * 16 + l15;
        if constexpr (NS == 2) {
          const float* yp = reinterpret_cast<const float*>(out) + row * DIM + koff;
          float4 v0 = *(const float4*)yp;
          float4 v1 = *(const float4*)(yp + 4);
          float tmp[8] = {v0.x, v0.y, v0.z, v0.w, v1.x, v1.y, v1.z, v1.w};
          split8(tmp, Ah[fi], Al[fi]);
        } else {
          const unsigned short* yp = reinterpret_cast<const unsigned short*>(out) + row * DIM + koff;
          Ah[fi] = *(const bf16x8*)yp;
        }
      }
      const int kb = ks * 32 + l4 * 8;
#pragma unroll
      for (int ni = 0; ni < 8; ++ni) {
        int off = (wcol + ni * 16 + l15) * 72 + kb;
        bf16x8 Bhf = *(const bf16x8*)(wh + off);
#pragma unroll
        for (int fi = 0; fi < 2; ++fi)
          acc[fi][ni] = __builtin_amdgcn_mfma_f32_16x16x32_bf16(Ah[fi], Bhf, acc[fi][ni], 0, 0, 0);
        if constexpr (NS == 2) {
          bf16x8 Blf = *(const bf16x8*)(wl + off);
#pragma unroll
          for (int fi = 0; fi < 2; ++fi) {
            acc[fi][ni] = __builtin_amdgcn_mfma_f32_16x16x32_bf16(Ah[fi], Blf, acc[fi][ni], 0, 0, 0);
            acc[fi][ni] = __builtin_amdgcn_mfma_f32_16x16x32_bf16(Al[fi], Bhf, acc[fi][ni], 0, 0, 0);
          }
        }
      }
    }
    __syncthreads();   // all waves done reading out[] + wh before restage/epilogue
  }

  // epilogue: bias + in-place store
#pragma unroll
  for (int fi = 0; fi < 2; ++fi) {
    size_t rbase = r0 + wrow + fi * 16 + l4 * 4;
#pragma unroll
    for (int ni = 0; ni < 8; ++ni) {
      int col = wcol + ni * 16 + l15;
      float bias = ldf(proj_b, (size_t)col);
#pragma unroll
      for (int r = 0; r < 4; ++r)
        stf(out, (rbase + r) * DIM + col, acc[fi][ni][r] + bias);
    }
  }
}

// ================= legacy fallback (ws too small for weight pre-split) =================
template <typename T>
__global__ __launch_bounds__(256, 2)
void win_attn_kernel(const T* __restrict__ x, const T* __restrict__ maskp,
                     const T* __restrict__ qkv_w, const T* __restrict__ qkv_b,
                     const T* __restrict__ rpb_table, const int* __restrict__ rel_index,
                     T* __restrict__ out, const int* __restrict__ flag, int want)
{
  if (*flag != want) return;

  const int b = blockIdx.x;
  const int h = blockIdx.y;
  const int tid = threadIdx.x;
  const int tx = tid & 15;
  const int ty = tid >> 4;

  __shared__ __align__(16) float xst[64][68];
  __shared__ __align__(16) float wt[96][68];
  __shared__ __align__(16) float qs[NTOK][36];
  __shared__ __align__(16) float ks2[NTOK][36];
  __shared__ __align__(16) float vs[NTOK][36];
  __shared__ __align__(16) float sm[NTOK][52];

  const float SCALE = 0.17677669529663687f;

  float acc[4][6];
#pragma unroll
  for (int i = 0; i < 4; ++i)
#pragma unroll
    for (int m = 0; m < 6; ++m) acc[i][m] = 0.0f;

  const size_t xbase = (size_t)b * NTOK * DIM;

  for (int kt = 0; kt < DIM; kt += 64) {
    for (int i = tid; i < NTOK * 64; i += 256) {
      int n = i >> 6, kk = i & 63;
      xst[n][kk] = ldf(x, xbase + (size_t)n * DIM + kt + kk);
    }
    for (int i = tid; i < 96 * 64; i += 256) {
      int j = i >> 6, kk = i & 63;
      int c = j >> 5, d = j & 31;
      wt[j][kk] = ldf(qkv_w, (size_t)(c * DIM + h * DH + d) * DIM + kt + kk);
    }
    __syncthreads();

#pragma unroll 2
    for (int kk = 0; kk < 64; kk += 4) {
      float4 av[4], bv[6];
#pragma unroll
      for (int i = 0; i < 4; ++i) av[i] = *(const float4*)&xst[ty + 16 * i][kk];
#pragma unroll
      for (int m = 0; m < 6; ++m) bv[m] = *(const float4*)&wt[tx + 16 * m][kk];
#pragma unroll
      for (int i = 0; i < 4; ++i)
#pragma unroll
        for (int m = 0; m < 6; ++m) {
          acc[i][m] += av[i].x * bv[m].x;
          acc[i][m] += av[i].y * bv[m].y;
          acc[i][m] += av[i].z * bv[m].z;
          acc[i][m] += av[i].w * bv[m].w;
        }
    }
    __syncthreads();
  }

#pragma unroll
  for (int i = 0; i < 4; ++i) {
    int n = ty + 16 * i;
    if (n < NTOK) {
#pragma unroll
      for (int m = 0; m < 6; ++m) {
        int j = tx + 16 * m;
        int c = j >> 5, d = j & 31;
        float v = acc[i][m] + ldf(qkv_b, c * DIM + h * DH + d);
        if (c == 0)      qs[n][d] = v * SCALE;
        else if (c == 1) ks2[n][d] = v;
        else             vs[n][d] = v;
      }
    }
  }
  __syncthreads();

  const int w = b & 63;
  for (int e = tid; e < NTOK * NTOK; e += 256) {
    int i = e / 49, j = e % 49;
    const float4* qi = (const float4*)qs[i];
    const float4* kj = (const float4*)ks2[j];
    float s = 0.0f;
#pragma unroll
    for (int d4 = 0; d4 < 8; ++d4) {
      float4 a = qi[d4], c = kj[d4];
      s += a.x * c.x + a.y * c.y + a.z * c.z + a.w * c.w;
    }
    s += ldf(rpb_table, (size_t)rel_index[e] * NH + h);
    s += ldf(maskp, (size_t)w * NTOK * NTOK + e);
    sm[i][j] = s;
  }
  __syncthreads();

  if (tid < NTOK) {
    int i = tid;
    float mx = -3.4e38f;
    for (int j = 0; j < NTOK; ++j) mx = fmaxf(mx, sm[i][j]);
    float sum = 0.0f;
    for (int j = 0; j < NTOK; ++j) {
      float ev = __expf(sm[i][j] - mx);
      sm[i][j] = ev;
      sum += ev;
    }
    float inv = 1.0f / sum;
    for (int j = 0; j < NTOK; ++j) sm[i][j] *= inv;
  }
  __syncthreads();

  for (int e = tid; e < NTOK * DH; e += 256) {
    int i = e >> 5, d = e & 31;
    float o = 0.0f;
    for (int j = 0; j < NTOK; ++j) o += sm[i][j] * vs[j][d];
    stf(out, ((size_t)b * NTOK + i) * DIM + h * DH + d, o);
  }
}

template <typename T>
__global__ __launch_bounds__(256, 2)
void proj_kernel(T* __restrict__ out, const T* __restrict__ proj_w,
                 const T* __restrict__ proj_b, const int* __restrict__ flag, int want)
{
  if (*flag != want) return;

  const int tid = threadIdx.x;
  const int tx = tid & 15;
  const int ty = tid >> 4;
  const size_t r0 = (size_t)blockIdx.x * 32;

  __shared__ __align__(16) float xs[32][260];
  __shared__ __align__(16) float pwt[256][36];

  for (int i = tid; i < 32 * 256; i += 256) {
    int n = i >> 8, c = i & 255;
    xs[n][c] = ldf((const T*)out, (r0 + n) * DIM + c);
  }
  __syncthreads();

  float acc[2][16];
#pragma unroll
  for (int i = 0; i < 2; ++i)
#pragma unroll
    for (int m = 0; m < 16; ++m) acc[i][m] = 0.0f;

  for (int kt = 0; kt < DIM; kt += 32) {
    for (int i = tid; i < 256 * 32; i += 256) {
      int j = i >> 5, kk = i & 31;
      pwt[j][kk] = ldf(proj_w, (size_t)j * DIM + kt + kk);
    }
    __syncthreads();

#pragma unroll 2
    for (int kk = 0; kk < 32; kk += 4) {
      float4 av[2], bv[16];
#pragma unroll
      for (int i = 0; i < 2; ++i) av[i] = *(const float4*)&xs[ty + 16 * i][kt + kk];
#pragma unroll
      for (int m = 0; m < 16; ++m) bv[m] = *(const float4*)&pwt[tx + 16 * m][kk];
#pragma unroll
      for (int i = 0; i < 2; ++i)
#pragma unroll
        for (int m = 0; m < 16; ++m) {
          acc[i][m] += av[i].x * bv[m].x;
          acc[i][m] += av[i].y * bv[m].y;
          acc[i][m] += av[i].z * bv[m].z;
          acc[i][m] += av[i].w * bv[m].w;
        }
    }
    __syncthreads();
  }

#pragma unroll
  for (int i = 0; i < 2; ++i) {
    int n = ty + 16 * i;
#pragma unroll
    for (int m = 0; m < 16; ++m) {
      int c = tx + 16 * m;
      stf(out, (r0 + n) * DIM + c, acc[i][m] + ldf(proj_b, c));
    }
  }
}

extern "C" void kernel_launch(void* const* d_in, const int* in_sizes, int n_in,
                              void* d_out, int out_size, void* d_ws, size_t ws_size,
                              hipStream_t stream) {
  const void* x      = d_in[0];
  const void* maskp  = d_in[1];
  const void* qkv_w  = d_in[2];
  const void* qkv_b  = d_in[3];
  const void* proj_w = d_in[4];
  const void* proj_b = d_in[5];
  const void* rpb    = d_in[6];
  const int*  rel    = (const int*)d_in[7];

  int* flag = (int*)d_ws;
  dtype_detect_kernel<<<dim3(1), dim3(64), 0, stream>>>((const unsigned int*)x, flag);

  const size_t WS_NEED = 16 + 1048576;   // flag slot + pre-split weights
  if (ws_size >= WS_NEED) {
    unsigned short* wsb = (unsigned short*)((char*)d_ws + 16);

    prep_w_kernel<float><<<dim3(256), dim3(256), 0, stream>>>(
        (const float*)qkv_w, (const float*)proj_w, wsb, flag, 0);
    prep_w_kernel<__hip_bfloat16><<<dim3(256), dim3(256), 0, stream>>>(
        (const __hip_bfloat16*)qkv_w, (const __hip_bfloat16*)proj_w, wsb, flag, 1);

    dim3 gA(NB, NH);
    win_attn_mfma_kernel<float><<<gA, 256, 0, stream>>>(
        (const float*)x, (const float*)maskp, (const float*)qkv_b,
        (const float*)rpb, rel, wsb, (float*)d_out, flag, 0);
    win_attn_mfma_kernel<__hip_bfloat16><<<gA, 256, 0, stream>>>(
        (const __hip_bfloat16*)x, (const __hip_bfloat16*)maskp, (const __hip_bfloat16*)qkv_b,
        (const __hip_bfloat16*)rpb, rel, wsb, (__hip_bfloat16*)d_out, flag, 1);

    proj_mfma_kernel<float><<<dim3(1568), 256, 0, stream>>>(
        (float*)d_out, wsb, (const float*)proj_b, flag, 0);
    proj_mfma_kernel<__hip_bfloat16><<<dim3(1568), 256, 0, stream>>>(
        (__hip_bfloat16*)d_out, wsb, (const __hip_bfloat16*)proj_b, flag, 1);
  } else {
    dim3 gA(NB, NH);
    win_attn_kernel<float><<<gA, 256, 0, stream>>>(
        (const float*)x, (const float*)maskp, (const float*)qkv_w, (const float*)qkv_b,
        (const float*)rpb, rel, (float*)d_out, flag, 0);
    win_attn_kernel<__hip_bfloat16><<<gA, 256, 0, stream>>>(
        (const __hip_bfloat16*)x, (const __hip_bfloat16*)maskp, (const __hip_bfloat16*)qkv_w,
        (const __hip_bfloat16*)qkv_b, (const __hip_bfloat16*)rpb, rel,
        (__hip_bfloat16*)d_out, flag, 1);

    dim3 gB(3136);
    proj_kernel<float><<<gB, 256, 0, stream>>>(
        (float*)d_out, (const float*)proj_w, (const float*)proj_b, flag, 0);
    proj_kernel<__hip_bfloat16><<<gB, 256, 0, stream>>>(
        (__hip_bfloat16*)d_out, (const __hip_bfloat16*)proj_w, (const __hip_bfloat16*)proj_b,
        flag, 1);
  }
}

// Round 2
// 706.972 us; speedup vs baseline: 2.4939x; 1.0644x over previous
//
#include <hip/hip_runtime.h>
#include <hip/hip_bf16.h>

#define NTOK 49
#define DIM  256
#define NH   8
#define DH   32
#define NB   2048

// ---------- MFMA fragment types ----------
typedef __attribute__((ext_vector_type(8))) short bf16x8;
typedef __attribute__((ext_vector_type(4))) float f32x4;

// ---------- bf16 split helpers (RNE, finite inputs only) ----------
__device__ __forceinline__ unsigned short f2bf(float f) {
  unsigned int u = __float_as_uint(f);
  return (unsigned short)((u + 0x7FFFu + ((u >> 16) & 1u)) >> 16);
}
__device__ __forceinline__ float bf2f(unsigned short h) {
  return __uint_as_float(((unsigned int)h) << 16);
}
__device__ __forceinline__ void split8(const float v[8], bf16x8& hv, bf16x8& lv) {
#pragma unroll
  for (int t = 0; t < 8; ++t) {
    unsigned short hb = f2bf(v[t]);
    hv[t] = (short)hb;
    lv[t] = (short)f2bf(v[t] - bf2f(hb));
  }
}

// ---------- dtype-polymorphic load/store ----------
__device__ __forceinline__ float ldf(const float* p, size_t i) { return p[i]; }
__device__ __forceinline__ float ldf(const __hip_bfloat16* p, size_t i) { return __bfloat162float(p[i]); }
__device__ __forceinline__ void stf(float* p, size_t i, float v) { p[i] = v; }
__device__ __forceinline__ void stf(__hip_bfloat16* p, size_t i, float v) { p[i] = __float2bfloat16(v); }

// ---------- dtype detector ----------
__global__ void dtype_detect_kernel(const unsigned int* __restrict__ x, int* flag) {
  if (blockIdx.x == 0 && threadIdx.x == 0) {
    int hits = 0;
    for (int i = 0; i < 64; ++i) {
      unsigned int lo = x[i] & 0xFFFFu;
      unsigned int e = (lo >> 7) & 0xFFu;
      if (e >= 110u && e <= 140u) hits++;
    }
    *flag = (hits >= 32) ? 1 : 0;   // 1 = bf16, 0 = fp32
  }
}

// ---------- workspace layout (ushorts, after 16-byte flag slot) ----------
#define OFF_QH 0
#define OFF_QL 196608
#define OFF_PH 393216
#define OFF_PL 458752

// ---------- prep: split weights into bf16 hi/lo in workspace ----------
template <typename T>
__global__ void prep_w_kernel(const T* __restrict__ qkv_w, const T* __restrict__ proj_w,
                              unsigned short* __restrict__ wsb,
                              const int* __restrict__ flag, int want) {
  if (*flag != want) return;
  int idx = blockIdx.x * blockDim.x + threadIdx.x;
  int stride = gridDim.x * blockDim.x;
  for (int i = idx; i < 768 * 256; i += stride) {
    float v = ldf(qkv_w, (size_t)i);
    unsigned short hb = f2bf(v);
    wsb[OFF_QH + i] = hb;
    wsb[OFF_QL + i] = f2bf(v - bf2f(hb));
  }
  for (int i = idx; i < 256 * 256; i += stride) {
    float v = ldf(proj_w, (size_t)i);
    unsigned short hb = f2bf(v);
    wsb[OFF_PH + i] = hb;
    wsb[OFF_PL + i] = f2bf(v - bf2f(hb));
  }
}

// ---------- fully-MFMA fused QKV + window attention ----------
// Block = (window b, head h), 256 threads / 4 waves.
// Phase 1: QKV GEMM  M=64(pad49) N=96 K=256, 16x16x32 bf16 MFMA, hi/lo x3 split (fp32 path).
// Phase 2: QK^T      M=64 N=64 K=32 MFMA (x3 split), +rpb+mask at C-write -> smx LDS.
// Phase 3: softmax   4 lanes/row (shfl_xor 16/32 reduce), probs -> bf16 hi/lo in LDS.
// Phase 4: PV        M=64 N=32 K=64 MFMA (x3 split), direct global store.
// LDS unions: staging (46080B fp32 / 23040 bf16)  vs  attn arrays:
//   qh/ql/kh/kl [64][40]us (20480) | vtT hi/lo [32][72]us (9216) | smx [64][60]f32 (15360) = 45056
//   p hi/lo [64][72]us (18432) aliases dead q/k region.  -> 46080B -> 3 blocks/CU.
template <typename T>
__global__ __launch_bounds__(256, 3)
void win_attn_mfma_kernel(const T* __restrict__ x, const T* __restrict__ maskp,
                          const T* __restrict__ qkv_b,
                          const T* __restrict__ rpb_table, const int* __restrict__ rel_index,
                          const unsigned short* __restrict__ wsb,
                          T* __restrict__ out, const int* __restrict__ flag, int want)
{
  if (*flag != want) return;
  constexpr int NS = (sizeof(T) == 4) ? 2 : 1;
  constexpr int SMEM_BYTES = (NS == 2) ? 46080 : 45056;
  __shared__ __align__(16) char smem[SMEM_BYTES];

  // phase-1 staging views
  unsigned short* xh = (unsigned short*)smem;           // [64][72]
  unsigned short* xl = xh + 64 * 72;                    // (NS==2)
  unsigned short* wh = xh + NS * 64 * 72;               // [96][72]
  unsigned short* wl = wh + 96 * 72;                    // (NS==2)
  // phase-2+ attention views (alias; staging dead by then)
  unsigned short* qh_ = (unsigned short*)smem;          // [64][40] q hi (pre-scaled)
  unsigned short* ql_ = qh_ + 64 * 40;
  unsigned short* kh_ = ql_ + 64 * 40;
  unsigned short* kl_ = kh_ + 64 * 40;                  // ends @20480B
  unsigned short* vth = kl_ + 64 * 40;                  // [32][72] V^T hi (rows=d, cols=j)
  unsigned short* vtl = vth + 32 * 72;                  // ends @29696B
  float* smx = (float*)(smem + 29696);                  // [64][60] scores
  unsigned short* ph_ = (unsigned short*)smem;          // [64][72] P hi (alias q/k)
  unsigned short* pl_ = ph_ + 64 * 72;                  // ends @18432B < 20480B

  const int b = blockIdx.x, h = blockIdx.y;
  const int tid = threadIdx.x;
  const int lane = tid & 63, wid = tid >> 6;
  const int l15 = lane & 15, l4 = lane >> 4;
  const int wrow = (wid & 1) * 32;            // GEMM & QK^T row base
  const int wcol6 = (wid >> 1) * 48;          // GEMM col base (N=96)
  const int wcol4 = (wid >> 1) * 32;          // QK^T col base (N=64)
  const float SCALE = 0.17677669529663687f;   // 32^-0.5
  const size_t xbase = (size_t)b * NTOK * DIM;
  const unsigned short* qwh = wsb + OFF_QH;
  const unsigned short* qwl = wsb + OFF_QL;

  // ================= Phase 1: QKV GEMM =================
  f32x4 acc[2][3];
#pragma unroll
  for (int fi = 0; fi < 2; ++fi)
#pragma unroll
    for (int ni = 0; ni < 3; ++ni) acc[fi][ni] = (f32x4){0.f, 0.f, 0.f, 0.f};

  for (int kt = 0; kt < DIM; kt += 64) {
    if constexpr (NS == 2) {
      const float* xf = reinterpret_cast<const float*>(x);
      for (int i = tid; i < NTOK * 16; i += 256) {
        int n = i >> 4, k4 = (i & 15) * 4;
        const float4 v = *(const float4*)(xf + xbase + n * DIM + kt + k4);
        ushort4 hh, ll;
        hh.x = f2bf(v.x); ll.x = f2bf(v.x - bf2f(hh.x));
        hh.y = f2bf(v.y); ll.y = f2bf(v.y - bf2f(hh.y));
        hh.z = f2bf(v.z); ll.z = f2bf(v.z - bf2f(hh.z));
        hh.w = f2bf(v.w); ll.w = f2bf(v.w - bf2f(hh.w));
        *(ushort4*)(xh + n * 72 + k4) = hh;
        *(ushort4*)(xl + n * 72 + k4) = ll;
      }
    } else {
      const unsigned short* xu = reinterpret_cast<const unsigned short*>(x);
      for (int i = tid; i < NTOK * 8; i += 256) {
        int n = i >> 3, k8 = (i & 7) * 8;
        *(int4*)(xh + n * 72 + k8) = *(const int4*)(xu + xbase + n * DIM + kt + k8);
      }
    }
    for (int i = tid; i < 96 * 8; i += 256) {
      int j = i >> 3, k8 = (i & 7) * 8;
      int G = (j >> 5) * DIM + h * DH + (j & 31);
      *(int4*)(wh + j * 72 + k8) = *(const int4*)(qwh + (size_t)G * DIM + kt + k8);
      if constexpr (NS == 2)
        *(int4*)(wl + j * 72 + k8) = *(const int4*)(qwl + (size_t)G * DIM + kt + k8);
    }
    __syncthreads();

#pragma unroll
    for (int ks = 0; ks < 2; ++ks) {
      const int ka = ks * 32 + l4 * 8;
      bf16x8 Ah[2], Al[2], Bh[3], Bl[3];
#pragma unroll
      for (int fi = 0; fi < 2; ++fi) {
        int off = (wrow + fi * 16 + l15) * 72 + ka;
        Ah[fi] = *(const bf16x8*)(xh + off);
        if constexpr (NS == 2) Al[fi] = *(const bf16x8*)(xl + off);
      }
#pragma unroll
      for (int ni = 0; ni < 3; ++ni) {
        int off = (wcol6 + ni * 16 + l15) * 72 + ka;
        Bh[ni] = *(const bf16x8*)(wh + off);
        if constexpr (NS == 2) Bl[ni] = *(const bf16x8*)(wl + off);
      }
#pragma unroll
      for (int fi = 0; fi < 2; ++fi)
#pragma unroll
        for (int ni = 0; ni < 3; ++ni) {
          acc[fi][ni] = __builtin_amdgcn_mfma_f32_16x16x32_bf16(Ah[fi], Bh[ni], acc[fi][ni], 0, 0, 0);
          if constexpr (NS == 2) {
            acc[fi][ni] = __builtin_amdgcn_mfma_f32_16x16x32_bf16(Ah[fi], Bl[ni], acc[fi][ni], 0, 0, 0);
            acc[fi][ni] = __builtin_amdgcn_mfma_f32_16x16x32_bf16(Al[fi], Bh[ni], acc[fi][ni], 0, 0, 0);
          }
        }
    }
    __syncthreads();
  }

  // ---- epilogue: bias (+scale q), split to bf16 hi/lo q/k tiles + V^T tile ----
  // C layout: col = l15, row = l4*4 + r
#pragma unroll
  for (int fi = 0; fi < 2; ++fi) {
    int rbase = wrow + fi * 16 + l4 * 4;
#pragma unroll
    for (int ni = 0; ni < 3; ++ni) {
      int j = wcol6 + ni * 16 + l15;
      int c = j >> 5, d = j & 31;
      float bias = ldf(qkv_b, (size_t)(c * DIM + h * DH + d));
#pragma unroll
      for (int r = 0; r < 4; ++r) {
        int row = rbase + r;
        if (row < NTOK) {
          float val = acc[fi][ni][r] + bias;
          if (c == 0) {
            val *= SCALE;
            unsigned short hb = f2bf(val);
            qh_[row * 40 + d] = hb;
            ql_[row * 40 + d] = f2bf(val - bf2f(hb));
          } else if (c == 1) {
            unsigned short hb = f2bf(val);
            kh_[row * 40 + d] = hb;
            kl_[row * 40 + d] = f2bf(val - bf2f(hb));
          } else {
            unsigned short hb = f2bf(val);
            vth[d * 72 + row] = hb;         // transposed: row=d, col=j(token)
            vtl[d * 72 + row] = f2bf(val - bf2f(hb));
          }
        }
      }
    }
  }
  // zero V^T pad tokens j=49..63 (K-dim of PV: 0*garbage would NaN-poison)
  for (int i = tid; i < 32 * 15; i += 256) {
    int d = i / 15, j2 = 49 + i % 15;
    vth[d * 72 + j2] = 0;
    vtl[d * 72 + j2] = 0;
  }
  __syncthreads();

  // ================= Phase 2: QK^T (M=64,N=64,K=32) + rpb + mask =================
  {
    f32x4 sacc[2][2];
#pragma unroll
    for (int fi = 0; fi < 2; ++fi)
#pragma unroll
      for (int nj = 0; nj < 2; ++nj) sacc[fi][nj] = (f32x4){0.f, 0.f, 0.f, 0.f};

    const int ka = l4 * 8;   // K=32: one k-step
    bf16x8 Aq_h[2], Aq_l[2], Bk_h[2], Bk_l[2];
#pragma unroll
    for (int fi = 0; fi < 2; ++fi) {
      int off = (wrow + fi * 16 + l15) * 40 + ka;
      Aq_h[fi] = *(const bf16x8*)(qh_ + off);
      Aq_l[fi] = *(const bf16x8*)(ql_ + off);
    }
#pragma unroll
    for (int nj = 0; nj < 2; ++nj) {
      int off = (wcol4 + nj * 16 + l15) * 40 + ka;
      Bk_h[nj] = *(const bf16x8*)(kh_ + off);
      Bk_l[nj] = *(const bf16x8*)(kl_ + off);
    }
#pragma unroll
    for (int fi = 0; fi < 2; ++fi)
#pragma unroll
      for (int nj = 0; nj < 2; ++nj) {
        sacc[fi][nj] = __builtin_amdgcn_mfma_f32_16x16x32_bf16(Aq_h[fi], Bk_h[nj], sacc[fi][nj], 0, 0, 0);
        sacc[fi][nj] = __builtin_amdgcn_mfma_f32_16x16x32_bf16(Aq_h[fi], Bk_l[nj], sacc[fi][nj], 0, 0, 0);
        sacc[fi][nj] = __builtin_amdgcn_mfma_f32_16x16x32_bf16(Aq_l[fi], Bk_h[nj], sacc[fi][nj], 0, 0, 0);
      }

    const int w = b & 63;
#pragma unroll
    for (int fi = 0; fi < 2; ++fi) {
#pragma unroll
      for (int nj = 0; nj < 2; ++nj) {
        int col = wcol4 + nj * 16 + l15;
#pragma unroll
        for (int r = 0; r < 4; ++r) {
          int row = wrow + fi * 16 + l4 * 4 + r;
          if (row < NTOK && col < NTOK) {
            int e = row * NTOK + col;
            float s = sacc[fi][nj][r];
            s += ldf(rpb_table, (size_t)rel_index[e] * NH + h);
            s += ldf(maskp, (size_t)w * NTOK * NTOK + e);
            smx[row * 60 + col] = s;
          }
        }
      }
    }
  }
  __syncthreads();

  // ================= Phase 3: wave-parallel softmax + P->bf16 hi/lo =================
  // row = wid*16 + l15 (rows>=49 compute garbage, isolated); quarter l4 owns j in [l4*16, l4*16+16)
  {
    const int row = wid * 16 + l15;
    const int j0 = l4 * 16;
    const float NEG = -3.4e38f;
    float vals[16];
#pragma unroll
    for (int t = 0; t < 16; ++t) {
      int j = j0 + t;
      vals[t] = (j < NTOK) ? smx[row * 60 + j] : NEG;
    }
    float mx = NEG;
#pragma unroll
    for (int t = 0; t < 16; ++t) mx = fmaxf(mx, vals[t]);
    mx = fmaxf(mx, __shfl_xor(mx, 16));
    mx = fmaxf(mx, __shfl_xor(mx, 32));
    float sum = 0.f;
#pragma unroll
    for (int t = 0; t < 16; ++t) {
      int j = j0 + t;
      float ev = (j < NTOK) ? __expf(vals[t] - mx) : 0.f;
      vals[t] = ev;
      sum += ev;
    }
    sum += __shfl_xor(sum, 16);
    sum += __shfl_xor(sum, 32);
    float inv = 1.f / sum;
    bf16x8 h0, h1, l0, l1;
#pragma unroll
    for (int t = 0; t < 8; ++t) {
      float p = vals[t] * inv;
      unsigned short hb = f2bf(p);
      h0[t] = (short)hb; l0[t] = (short)f2bf(p - bf2f(hb));
    }
#pragma unroll
    for (int t = 0; t < 8; ++t) {
      float p = vals[8 + t] * inv;
      unsigned short hb = f2bf(p);
      h1[t] = (short)hb; l1[t] = (short)f2bf(p - bf2f(hb));
    }
    *(bf16x8*)(ph_ + row * 72 + j0)     = h0;
    *(bf16x8*)(ph_ + row * 72 + j0 + 8) = h1;
    *(bf16x8*)(pl_ + row * 72 + j0)     = l0;
    *(bf16x8*)(pl_ + row * 72 + j0 + 8) = l1;
  }
  __syncthreads();

  // ================= Phase 4: PV (M=64,N=32,K=64) =================
  {
    f32x4 oacc[2];
#pragma unroll
    for (int nc = 0; nc < 2; ++nc) oacc[nc] = (f32x4){0.f, 0.f, 0.f, 0.f};

#pragma unroll
    for (int ks = 0; ks < 2; ++ks) {
      const int kk = ks * 32 + l4 * 8;
      const int arow = wid * 16 + l15;
      bf16x8 Ap_h = *(const bf16x8*)(ph_ + arow * 72 + kk);
      bf16x8 Ap_l = *(const bf16x8*)(pl_ + arow * 72 + kk);
#pragma unroll
      for (int nc = 0; nc < 2; ++nc) {
        int bcol = nc * 16 + l15;
        bf16x8 Bv_h = *(const bf16x8*)(vth + bcol * 72 + kk);
        bf16x8 Bv_l = *(const bf16x8*)(vtl + bcol * 72 + kk);
        oacc[nc] = __builtin_amdgcn_mfma_f32_16x16x32_bf16(Ap_h, Bv_h, oacc[nc], 0, 0, 0);
        oacc[nc] = __builtin_amdgcn_mfma_f32_16x16x32_bf16(Ap_h, Bv_l, oacc[nc], 0, 0, 0);
        oacc[nc] = __builtin_amdgcn_mfma_f32_16x16x32_bf16(Ap_l, Bv_h, oacc[nc], 0, 0, 0);
      }
    }
#pragma unroll
    for (int nc = 0; nc < 2; ++nc) {
      int d = nc * 16 + l15;
#pragma unroll
      for (int r = 0; r < 4; ++r) {
        int row = wid * 16 + l4 * 4 + r;
        if (row < NTOK)
          stf(out, ((size_t)b * NTOK + row) * DIM + h * DH + d, oacc[nc][r]);
      }
    }
  }
}

// ---------- MFMA in-place output projection (unchanged from round 1) ----------
template <typename T>
__global__ __launch_bounds__(256, 2)
void proj_mfma_kernel(T* __restrict__ out, const unsigned short* __restrict__ wsb,
                      const T* __restrict__ proj_b, const int* __restrict__ flag, int want)
{
  if (*flag != want) return;
  constexpr int NS = (sizeof(T) == 4) ? 2 : 1;
  constexpr int SMEM_BYTES = NS * 256 * 72 * 2;
  __shared__ __align__(16) char smem[SMEM_BYTES];
  unsigned short* wh = (unsigned short*)smem;
  unsigned short* wl = wh + 256 * 72;

  const int tid = threadIdx.x;
  const int lane = tid & 63, wid = tid >> 6;
  const int wrow = (wid & 1) * 32, wcol = (wid >> 1) * 128;
  const int l15 = lane & 15, l4 = lane >> 4;
  const size_t r0 = (size_t)blockIdx.x * 64;
  const unsigned short* ph = wsb + OFF_PH;
  const unsigned short* pl = wsb + OFF_PL;

  f32x4 acc[2][8];
#pragma unroll
  for (int fi = 0; fi < 2; ++fi)
#pragma unroll
    for (int ni = 0; ni < 8; ++ni) acc[fi][ni] = (f32x4){0.f, 0.f, 0.f, 0.f};

  for (int kt = 0; kt < DIM; kt += 64) {
    for (int i = tid; i < 256 * 8; i += 256) {
      int j = i >> 3, k8 = (i & 7) * 8;
      *(int4*)(wh + j * 72 + k8) = *(const int4*)(ph + (size_t)j * DIM + kt + k8);
      if constexpr (NS == 2)
        *(int4*)(wl + j * 72 + k8) = *(const int4*)(pl + (size_t)j * DIM + kt + k8);
    }
    __syncthreads();

#pragma unroll
    for (int ks = 0; ks < 2; ++ks) {
      const int koff = kt + ks * 32 + l4 * 8;
      bf16x8 Ah[2], Al[2];
#pragma unroll
      for (int fi = 0; fi < 2; ++fi) {
        size_t row = r0 + wrow + fi * 16 + l15;
        if constexpr (NS == 2) {
          const float* yp = reinterpret_cast<const float*>(out) + row * DIM + koff;
          float4 v0 = *(const float4*)yp;
          float4 v1 = *(const float4*)(yp + 4);
          float tmp[8] = {v0.x, v0.y, v0.z, v0.w, v1.x, v1.y, v1.z, v1.w};
          split8(tmp, Ah[fi], Al[fi]);
        } else {
          const unsigned short* yp = reinterpret_cast<const unsigned short*>(out) + row * DIM + koff;
          Ah[fi] = *(const bf16x8*)yp;
        }
      }
      const int kb = ks * 32 + l4 * 8;
#pragma unroll
      for (int ni = 0; ni < 8; ++ni) {
        int off = (wcol + ni * 16 + l15) * 72 + kb;
        bf16x8 Bhf = *(const bf16x8*)(wh + off);
#pragma unroll
        for (int fi = 0; fi < 2; ++fi)
          acc[fi][ni] = __builtin_amdgcn_mfma_f32_16x16x32_bf16(Ah[fi], Bhf, acc[fi][ni], 0, 0, 0);
        if constexpr (NS == 2) {
          bf16x8 Blf = *(const bf16x8*)(wl + off);
#pragma unroll
          for (int fi = 0; fi < 2; ++fi) {
            acc[fi][ni] = __builtin_amdgcn_mfma_f32_16x16x32_bf16(Ah[fi], Blf, acc[fi][ni], 0, 0, 0);
            acc[fi][ni] = __builtin_amdgcn_mfma_f32_16x16x32_bf16(Al[fi], Bhf, acc[fi][ni], 0, 0, 0);
          }
        }
      }
    }
    __syncthreads();
  }

#pragma unroll
  for (int fi = 0; fi < 2; ++fi) {
    size_t rbase = r0 + wrow + fi * 16 + l4 * 4;
#pragma unroll
    for (int ni = 0; ni < 8; ++ni) {
      int col = wcol + ni * 16 + l15;
      float bias = ldf(proj_b, (size_t)col);
#pragma unroll
      for (int r = 0; r < 4; ++r)
        stf(out, (rbase + r) * DIM + col, acc[fi][ni][r] + bias);
    }
  }
}

// ================= legacy fallback (ws too small for weight pre-split) =================
template <typename T>
__global__ __launch_bounds__(256, 2)
void win_attn_kernel(const T* __restrict__ x, const T* __restrict__ maskp,
                     const T* __restrict__ qkv_w, const T* __restrict__ qkv_b,
                     const T* __restrict__ rpb_table, const int* __restrict__ rel_index,
                     T* __restrict__ out, const int* __restrict__ flag, int want)
{
  if (*flag != want) return;

  const int b = blockIdx.x;
  const int h = blockIdx.y;
  const int tid = threadIdx.x;
  const int tx = tid & 15;
  const int ty = tid >> 4;

  __shared__ __align__(16) float xst[64][68];
  __shared__ __align__(16) float wt[96][68];
  __shared__ __align__(16) float qs[NTOK][36];
  __shared__ __align__(16) float ks2[NTOK][36];
  __shared__ __align__(16) float vs[NTOK][36];
  __shared__ __align__(16) float sm[NTOK][52];

  const float SCALE = 0.17677669529663687f;

  float acc[4][6];
#pragma unroll
  for (int i = 0; i < 4; ++i)
#pragma unroll
    for (int m = 0; m < 6; ++m) acc[i][m] = 0.0f;

  const size_t xbase = (size_t)b * NTOK * DIM;

  for (int kt = 0; kt < DIM; kt += 64) {
    for (int i = tid; i < NTOK * 64; i += 256) {
      int n = i >> 6, kk = i & 63;
      xst[n][kk] = ldf(x, xbase + (size_t)n * DIM + kt + kk);
    }
    for (int i = tid; i < 96 * 64; i += 256) {
      int j = i >> 6, kk = i & 63;
      int c = j >> 5, d = j & 31;
      wt[j][kk] = ldf(qkv_w, (size_t)(c * DIM + h * DH + d) * DIM + kt + kk);
    }
    __syncthreads();

#pragma unroll 2
    for (int kk = 0; kk < 64; kk += 4) {
      float4 av[4], bv[6];
#pragma unroll
      for (int i = 0; i < 4; ++i) av[i] = *(const float4*)&xst[ty + 16 * i][kk];
#pragma unroll
      for (int m = 0; m < 6; ++m) bv[m] = *(const float4*)&wt[tx + 16 * m][kk];
#pragma unroll
      for (int i = 0; i < 4; ++i)
#pragma unroll
        for (int m = 0; m < 6; ++m) {
          acc[i][m] += av[i].x * bv[m].x;
          acc[i][m] += av[i].y * bv[m].y;
          acc[i][m] += av[i].z * bv[m].z;
          acc[i][m] += av[i].w * bv[m].w;
        }
    }
    __syncthreads();
  }

#pragma unroll
  for (int i = 0; i < 4; ++i) {
    int n = ty + 16 * i;
    if (n < NTOK) {
#pragma unroll
      for (int m = 0; m < 6; ++m) {
        int j = tx + 16 * m;
        int c = j >> 5, d = j & 31;
        float v = acc[i][m] + ldf(qkv_b, c * DIM + h * DH + d);
        if (c == 0)      qs[n][d] = v * SCALE;
        else if (c == 1) ks2[n][d] = v;
        else             vs[n][d] = v;
      }
    }
  }
  __syncthreads();

  const int w = b & 63;
  for (int e = tid; e < NTOK * NTOK; e += 256) {
    int i = e / 49, j = e % 49;
    const float4* qi = (const float4*)qs[i];
    const float4* kj = (const float4*)ks2[j];
    float s = 0.0f;
#pragma unroll
    for (int d4 = 0; d4 < 8; ++d4) {
      float4 a = qi[d4], c = kj[d4];
      s += a.x * c.x + a.y * c.y + a.z * c.z + a.w * c.w;
    }
    s += ldf(rpb_table, (size_t)rel_index[e] * NH + h);
    s += ldf(maskp, (size_t)w * NTOK * NTOK + e);
    sm[i][j] = s;
  }
  __syncthreads();

  if (tid < NTOK) {
    int i = tid;
    float mx = -3.4e38f;
    for (int j = 0; j < NTOK; ++j) mx = fmaxf(mx, sm[i][j]);
    float sum = 0.0f;
    for (int j = 0; j < NTOK; ++j) {
      float ev = __expf(sm[i][j] - mx);
      sm[i][j] = ev;
      sum += ev;
    }
    float inv = 1.0f / sum;
    for (int j = 0; j < NTOK; ++j) sm[i][j] *= inv;
  }
  __syncthreads();

  for (int e = tid; e < NTOK * DH; e += 256) {
    int i = e >> 5, d = e & 31;
    float o = 0.0f;
    for (int j = 0; j < NTOK; ++j) o += sm[i][j] * vs[j][d];
    stf(out, ((size_t)b * NTOK + i) * DIM + h * DH + d, o);
  }
}

template <typename T>
__global__ __launch_bounds__(256, 2)
void proj_kernel(T* __restrict__ out, const T* __restrict__ proj_w,
                 const T* __restrict__ proj_b, const int* __restrict__ flag, int want)
{
  if (*flag != want) return;

  const int tid = threadIdx.x;
  const int tx = tid & 15;
  const int ty = tid >> 4;
  const size_t r0 = (size_t)blockIdx.x * 32;

  __shared__ __align__(16) float xs[32][260];
  __shared__ __align__(16) float pwt[256][36];

  for (int i = tid; i < 32 * 256; i += 256) {
    int n = i >> 8, c = i & 255;
    xs[n][c] = ldf((const T*)out, (r0 + n) * DIM + c);
  }
  __syncthreads();

  float acc[2][16];
#pragma unroll
  for (int i = 0; i < 2; ++i)
#pragma unroll
    for (int m = 0; m < 16; ++m) acc[i][m] = 0.0f;

  for (int kt = 0; kt < DIM; kt += 32) {
    for (int i = tid; i < 256 * 32; i += 256) {
      int j = i >> 5, kk = i & 31;
      pwt[j][kk] = ldf(proj_w, (size_t)j * DIM + kt + kk);
    }
    __syncthreads();

#pragma unroll 2
    for (int kk = 0; kk < 32; kk += 4) {
      float4 av[2], bv[16];
#pragma unroll
      for (int i = 0; i < 2; ++i) av[i] = *(const float4*)&xs[ty + 16 * i][kt + kk];
#pragma unroll
      for (int m = 0; m < 16; ++m) bv[m] = *(const float4*)&pwt[tx + 16 * m][kk];
#pragma unroll
      for (int i = 0; i < 2; ++i)
#pragma unroll
        for (int m = 0; m < 16; ++m) {
          acc[i][m] += av[i].x * bv[m].x;
          acc[i][m] += av[i].y * bv[m].y;
          acc[i][m] += av[i].z * bv[m].z;
          acc[i][m] += av[i].w * bv[m].w;
        }
    }
    __syncthreads();
  }

#pragma unroll
  for (int i = 0; i < 2; ++i) {
    int n = ty + 16 * i;
#pragma unroll
    for (int m = 0; m < 16; ++m) {
      int c = tx + 16 * m;
      stf(out, (r0 + n) * DIM + c, acc[i][m] + ldf(proj_b, c));
    }
  }
}

extern "C" void kernel_launch(void* const* d_in, const int* in_sizes, int n_in,
                              void* d_out, int out_size, void* d_ws, size_t ws_size,
                              hipStream_t stream) {
  const void* x      = d_in[0];
  const void* maskp  = d_in[1];
  const void* qkv_w  = d_in[2];
  const void* qkv_b  = d_in[3];
  const void* proj_w = d_in[4];
  const void* proj_b = d_in[5];
  const void* rpb    = d_in[6];
  const int*  rel    = (const int*)d_in[7];

  int* flag = (int*)d_ws;
  dtype_detect_kernel<<<dim3(1), dim3(64), 0, stream>>>((const unsigned int*)x, flag);

  const size_t WS_NEED = 16 + 1048576;
  if (ws_size >= WS_NEED) {
    unsigned short* wsb = (unsigned short*)((char*)d_ws + 16);

    prep_w_kernel<float><<<dim3(256), dim3(256), 0, stream>>>(
        (const float*)qkv_w, (const float*)proj_w, wsb, flag, 0);
    prep_w_kernel<__hip_bfloat16><<<dim3(256), dim3(256), 0, stream>>>(
        (const __hip_bfloat16*)qkv_w, (const __hip_bfloat16*)proj_w, wsb, flag, 1);

    dim3 gA(NB, NH);
    win_attn_mfma_kernel<float><<<gA, 256, 0, stream>>>(
        (const float*)x, (const float*)maskp, (const float*)qkv_b,
        (const float*)rpb, rel, wsb, (float*)d_out, flag, 0);
    win_attn_mfma_kernel<__hip_bfloat16><<<gA, 256, 0, stream>>>(
        (const __hip_bfloat16*)x, (const __hip_bfloat16*)maskp, (const __hip_bfloat16*)qkv_b,
        (const __hip_bfloat16*)rpb, rel, wsb, (__hip_bfloat16*)d_out, flag, 1);

    proj_mfma_kernel<float><<<dim3(1568), 256, 0, stream>>>(
        (float*)d_out, wsb, (const float*)proj_b, flag, 0);
    proj_mfma_kernel<__hip_bfloat16><<<dim3(1568), 256, 0, stream>>>(
        (__hip_bfloat16*)d_out, wsb, (const __hip_bfloat16*)proj_b, flag, 1);
  } else {
    dim3 gA(NB, NH);
    win_attn_kernel<float><<<gA, 256, 0, stream>>>(
        (const float*)x, (const float*)maskp, (const float*)qkv_w, (const float*)qkv_b,
        (const float*)rpb, rel, (float*)d_out, flag, 0);
    win_attn_kernel<__hip_bfloat16><<<gA, 256, 0, stream>>>(
        (const __hip_bfloat16*)x, (const __hip_bfloat16*)maskp, (const __hip_bfloat16*)qkv_w,
        (const __hip_bfloat16*)qkv_b, (const __hip_bfloat16*)rpb, rel,
        (__hip_bfloat16*)d_out, flag, 1);

    dim3 gB(3136);
    proj_kernel<float><<<gB, 256, 0, stream>>>(
        (float*)d_out, (const float*)proj_w, (const float*)proj_b, flag, 0);
    proj_kernel<__hip_bfloat16><<<gB, 256, 0, stream>>>(
        (__hip_bfloat16*)d_out, (const __hip_bfloat16*)proj_w, (const __hip_bfloat16*)proj_b,
        flag, 1);
  }
}

// Round 3
// 694.972 us; speedup vs baseline: 2.5369x; 1.0173x over previous
//
#include <hip/hip_runtime.h>
#include <hip/hip_bf16.h>

#define NTOK 49
#define DIM  256
#define NH   8
#define DH   32
#define NB   2048

// ---------- MFMA fragment types ----------
typedef __attribute__((ext_vector_type(8))) short bf16x8;
typedef __attribute__((ext_vector_type(4))) float f32x4;

// ---------- bf16 split helpers (RNE, finite inputs only) ----------
__device__ __forceinline__ unsigned short f2bf(float f) {
  unsigned int u = __float_as_uint(f);
  return (unsigned short)((u + 0x7FFFu + ((u >> 16) & 1u)) >> 16);
}
__device__ __forceinline__ float bf2f(unsigned short h) {
  return __uint_as_float(((unsigned int)h) << 16);
}

// ---------- dtype-polymorphic load/store ----------
__device__ __forceinline__ float ldf(const float* p, size_t i) { return p[i]; }
__device__ __forceinline__ float ldf(const __hip_bfloat16* p, size_t i) { return __bfloat162float(p[i]); }
__device__ __forceinline__ void stf(float* p, size_t i, float v) { p[i] = v; }
__device__ __forceinline__ void stf(__hip_bfloat16* p, size_t i, float v) { p[i] = __float2bfloat16(v); }

// ---------- dtype detector ----------
__global__ void dtype_detect_kernel(const unsigned int* __restrict__ x, int* flag) {
  if (blockIdx.x == 0 && threadIdx.x == 0) {
    int hits = 0;
    for (int i = 0; i < 64; ++i) {
      unsigned int lo = x[i] & 0xFFFFu;
      unsigned int e = (lo >> 7) & 0xFFu;
      if (e >= 110u && e <= 140u) hits++;
    }
    *flag = (hits >= 32) ? 1 : 0;   // 1 = bf16, 0 = fp32
  }
}

// ---------- workspace layout (ushorts, after 16-byte flag slot) ----------
#define OFF_QH 0
#define OFF_QL 196608
#define OFF_PH 393216
#define OFF_PL 458752

// ---------- prep: split weights into bf16 hi/lo in workspace ----------
template <typename T>
__global__ void prep_w_kernel(const T* __restrict__ qkv_w, const T* __restrict__ proj_w,
                              unsigned short* __restrict__ wsb,
                              const int* __restrict__ flag, int want) {
  if (*flag != want) return;
  int idx = blockIdx.x * blockDim.x + threadIdx.x;
  int stride = gridDim.x * blockDim.x;
  for (int i = idx; i < 768 * 256; i += stride) {
    float v = ldf(qkv_w, (size_t)i);
    unsigned short hb = f2bf(v);
    wsb[OFF_QH + i] = hb;
    wsb[OFF_QL + i] = f2bf(v - bf2f(hb));
  }
  for (int i = idx; i < 256 * 256; i += stride) {
    float v = ldf(proj_w, (size_t)i);
    unsigned short hb = f2bf(v);
    wsb[OFF_PH + i] = hb;
    wsb[OFF_PL + i] = f2bf(v - bf2f(hb));
  }
}

// ---------- head-merged fully-MFMA fused QKV + window attention ----------
// Block = (window b, head-quad). 256 threads / 4 waves; wave w owns head hbase+w.
// Phase 1: QKV GEMM  per wave M=64(pad49) N=96 K=256, BK=64 x-staging (shared),
//          B-frags (pre-split hi/lo) read DIRECTLY from global/L2 (no w staging).
// Then loop hh=0..3: epilogue(wave hh) -> QK^T -> softmax -> PV (all waves), as round 2.
// fp32 path stores attn-out as packed {bf16hi,bf16lo} u32 (consumed+replaced by proj).
// LDS: x stage (18432B fp32 / 9216 bf16) UNION attn scratch 45056B -> 45056B -> 2 blocks/CU
//      (VGPR-capped: acc=96/wave).
template <typename T>
__global__ __launch_bounds__(256, 2)
void win_attn_mfma_kernel(const T* __restrict__ x, const T* __restrict__ maskp,
                          const T* __restrict__ qkv_b,
                          const T* __restrict__ rpb_table, const int* __restrict__ rel_index,
                          const unsigned short* __restrict__ wsb,
                          T* __restrict__ out, const int* __restrict__ flag, int want)
{
  if (*flag != want) return;
  constexpr int NS = (sizeof(T) == 4) ? 2 : 1;
  __shared__ __align__(16) char smem[45056];

  // phase-1 staging views (dead after GEMM)
  unsigned short* xh = (unsigned short*)smem;           // [64][72]
  unsigned short* xl = xh + 64 * 72;                    // (NS==2)
  // attention scratch views (alias; live after GEMM)
  unsigned short* qh_ = (unsigned short*)smem;          // [64][40] q hi (pre-scaled)
  unsigned short* ql_ = qh_ + 64 * 40;
  unsigned short* kh_ = ql_ + 64 * 40;
  unsigned short* kl_ = kh_ + 64 * 40;                  // ends @20480B
  unsigned short* vth = kl_ + 64 * 40;                  // [32][72] V^T hi (rows=d, cols=j)
  unsigned short* vtl = vth + 32 * 72;                  // ends @29696B
  float* smx = (float*)(smem + 29696);                  // [64][60] scores, ends @45056
  unsigned short* ph_ = (unsigned short*)smem;          // [64][72] P hi (alias q/k)
  unsigned short* pl_ = ph_ + 64 * 72;                  // ends @18432B

  const int b = blockIdx.x;
  const int hbase = blockIdx.y * 4;
  const int tid = threadIdx.x;
  const int lane = tid & 63, wid = tid >> 6;
  const int l15 = lane & 15, l4 = lane >> 4;
  const float SCALE = 0.17677669529663687f;
  const size_t xbase = (size_t)b * NTOK * DIM;
  const unsigned short* qwh = wsb + OFF_QH;
  const int myh = hbase + wid;                          // this wave's head

  // per-nfrag B row base (hi array; lo at +OFF_QL)
  size_t brow[6];
#pragma unroll
  for (int ni = 0; ni < 6; ++ni) {
    int j = ni * 16 + l15;
    brow[ni] = (size_t)((j >> 5) * DIM + myh * DH + (j & 31)) * DIM;
  }

  // ================= Phase 1: QKV GEMM (one head per wave) =================
  f32x4 acc[4][6];
#pragma unroll
  for (int mi = 0; mi < 4; ++mi)
#pragma unroll
    for (int ni = 0; ni < 6; ++ni) acc[mi][ni] = (f32x4){0.f, 0.f, 0.f, 0.f};

  for (int kt = 0; kt < DIM; kt += 64) {
    if constexpr (NS == 2) {
      const float* xf = reinterpret_cast<const float*>(x);
      for (int i = tid; i < NTOK * 16; i += 256) {
        int n = i >> 4, k4 = (i & 15) * 4;
        const float4 v = *(const float4*)(xf + xbase + n * DIM + kt + k4);
        ushort4 hh, ll;
        hh.x = f2bf(v.x); ll.x = f2bf(v.x - bf2f(hh.x));
        hh.y = f2bf(v.y); ll.y = f2bf(v.y - bf2f(hh.y));
        hh.z = f2bf(v.z); ll.z = f2bf(v.z - bf2f(hh.z));
        hh.w = f2bf(v.w); ll.w = f2bf(v.w - bf2f(hh.w));
        *(ushort4*)(xh + n * 72 + k4) = hh;
        *(ushort4*)(xl + n * 72 + k4) = ll;
      }
    } else {
      const unsigned short* xu = reinterpret_cast<const unsigned short*>(x);
      for (int i = tid; i < NTOK * 8; i += 256) {
        int n = i >> 3, k8 = (i & 7) * 8;
        *(int4*)(xh + n * 72 + k8) = *(const int4*)(xu + xbase + n * DIM + kt + k8);
      }
    }
    __syncthreads();

#pragma unroll
    for (int ks = 0; ks < 2; ++ks) {
      const int ka = ks * 32 + l4 * 8;
      bf16x8 Ah[4], Al[4];
#pragma unroll
      for (int mi = 0; mi < 4; ++mi) {
        int off = (mi * 16 + l15) * 72 + ka;
        Ah[mi] = *(const bf16x8*)(xh + off);
        if constexpr (NS == 2) Al[mi] = *(const bf16x8*)(xl + off);
      }
#pragma unroll
      for (int ni = 0; ni < 6; ++ni) {
        const unsigned short* bp = qwh + brow[ni] + kt + ka;
        bf16x8 Bh = *(const bf16x8*)bp;
#pragma unroll
        for (int mi = 0; mi < 4; ++mi)
          acc[mi][ni] = __builtin_amdgcn_mfma_f32_16x16x32_bf16(Ah[mi], Bh, acc[mi][ni], 0, 0, 0);
        if constexpr (NS == 2) {
          bf16x8 Bl = *(const bf16x8*)(bp + OFF_QL);
#pragma unroll
          for (int mi = 0; mi < 4; ++mi) {
            acc[mi][ni] = __builtin_amdgcn_mfma_f32_16x16x32_bf16(Ah[mi], Bl, acc[mi][ni], 0, 0, 0);
            acc[mi][ni] = __builtin_amdgcn_mfma_f32_16x16x32_bf16(Al[mi], Bh, acc[mi][ni], 0, 0, 0);
          }
        }
      }
    }
    __syncthreads();   // frag reads done before restage / scratch aliasing
  }

  // ================= per-head attention loop =================
  const int w = b & 63;
  for (int hh = 0; hh < 4; ++hh) {
    const int h = hbase + hh;

    // ---- epilogue by wave hh; other waves zero V^T pad tokens ----
    if (wid == hh) {
#pragma unroll
      for (int mi = 0; mi < 4; ++mi) {
        int rbase = mi * 16 + l4 * 4;
#pragma unroll
        for (int ni = 0; ni < 6; ++ni) {
          int j = ni * 16 + l15;
          int c = j >> 5, d = j & 31;
          float bias = ldf(qkv_b, (size_t)(c * DIM + h * DH + d));
#pragma unroll
          for (int r = 0; r < 4; ++r) {
            int row = rbase + r;
            if (row < NTOK) {
              float val = acc[mi][ni][r] + bias;
              if (c == 0) {
                val *= SCALE;
                unsigned short hb = f2bf(val);
                qh_[row * 40 + d] = hb;
                ql_[row * 40 + d] = f2bf(val - bf2f(hb));
              } else if (c == 1) {
                unsigned short hb = f2bf(val);
                kh_[row * 40 + d] = hb;
                kl_[row * 40 + d] = f2bf(val - bf2f(hb));
              } else {
                unsigned short hb = f2bf(val);
                vth[d * 72 + row] = hb;       // transposed: row=d, col=token
                vtl[d * 72 + row] = f2bf(val - bf2f(hb));
              }
            }
          }
        }
      }
    } else {
      // 3 idle waves zero V^T pads j=49..63 (disjoint from epilogue writes)
      int base = (wid < hh ? wid : wid - 1) * 64 + lane;
      for (int i = base; i < 32 * 15; i += 192) {
        int d = i / 15, j2 = 49 + i % 15;
        vth[d * 72 + j2] = 0;
        vtl[d * 72 + j2] = 0;
      }
    }
    __syncthreads();

    // ---- QK^T (M=64,N=64,K=32) + rpb + mask ----
    {
      const int wrow = (wid & 1) * 32;
      const int wcol4 = (wid >> 1) * 32;
      f32x4 sacc[2][2];
#pragma unroll
      for (int fi = 0; fi < 2; ++fi)
#pragma unroll
        for (int nj = 0; nj < 2; ++nj) sacc[fi][nj] = (f32x4){0.f, 0.f, 0.f, 0.f};

      const int ka = l4 * 8;
      bf16x8 Aq_h[2], Aq_l[2], Bk_h[2], Bk_l[2];
#pragma unroll
      for (int fi = 0; fi < 2; ++fi) {
        int off = (wrow + fi * 16 + l15) * 40 + ka;
        Aq_h[fi] = *(const bf16x8*)(qh_ + off);
        Aq_l[fi] = *(const bf16x8*)(ql_ + off);
      }
#pragma unroll
      for (int nj = 0; nj < 2; ++nj) {
        int off = (wcol4 + nj * 16 + l15) * 40 + ka;
        Bk_h[nj] = *(const bf16x8*)(kh_ + off);
        Bk_l[nj] = *(const bf16x8*)(kl_ + off);
      }
#pragma unroll
      for (int fi = 0; fi < 2; ++fi)
#pragma unroll
        for (int nj = 0; nj < 2; ++nj) {
          sacc[fi][nj] = __builtin_amdgcn_mfma_f32_16x16x32_bf16(Aq_h[fi], Bk_h[nj], sacc[fi][nj], 0, 0, 0);
          sacc[fi][nj] = __builtin_amdgcn_mfma_f32_16x16x32_bf16(Aq_h[fi], Bk_l[nj], sacc[fi][nj], 0, 0, 0);
          sacc[fi][nj] = __builtin_amdgcn_mfma_f32_16x16x32_bf16(Aq_l[fi], Bk_h[nj], sacc[fi][nj], 0, 0, 0);
        }

#pragma unroll
      for (int fi = 0; fi < 2; ++fi) {
#pragma unroll
        for (int nj = 0; nj < 2; ++nj) {
          int col = wcol4 + nj * 16 + l15;
#pragma unroll
          for (int r = 0; r < 4; ++r) {
            int row = wrow + fi * 16 + l4 * 4 + r;
            if (row < NTOK && col < NTOK) {
              int e = row * NTOK + col;
              float s = sacc[fi][nj][r];
              s += ldf(rpb_table, (size_t)rel_index[e] * NH + h);
              s += ldf(maskp, (size_t)w * NTOK * NTOK + e);
              smx[row * 60 + col] = s;
            }
          }
        }
      }
    }
    __syncthreads();

    // ---- wave-parallel softmax + P->bf16 hi/lo ----
    {
      const int row = wid * 16 + l15;
      const int j0 = l4 * 16;
      const float NEG = -3.4e38f;
      float vals[16];
#pragma unroll
      for (int t = 0; t < 16; ++t) {
        int j = j0 + t;
        vals[t] = (j < NTOK) ? smx[row * 60 + j] : NEG;
      }
      float mx = NEG;
#pragma unroll
      for (int t = 0; t < 16; ++t) mx = fmaxf(mx, vals[t]);
      mx = fmaxf(mx, __shfl_xor(mx, 16));
      mx = fmaxf(mx, __shfl_xor(mx, 32));
      float sum = 0.f;
#pragma unroll
      for (int t = 0; t < 16; ++t) {
        int j = j0 + t;
        float ev = (j < NTOK) ? __expf(vals[t] - mx) : 0.f;
        vals[t] = ev;
        sum += ev;
      }
      sum += __shfl_xor(sum, 16);
      sum += __shfl_xor(sum, 32);
      float inv = 1.f / sum;
      bf16x8 h0, h1, l0, l1;
#pragma unroll
      for (int t = 0; t < 8; ++t) {
        float p = vals[t] * inv;
        unsigned short hb = f2bf(p);
        h0[t] = (short)hb; l0[t] = (short)f2bf(p - bf2f(hb));
      }
#pragma unroll
      for (int t = 0; t < 8; ++t) {
        float p = vals[8 + t] * inv;
        unsigned short hb = f2bf(p);
        h1[t] = (short)hb; l1[t] = (short)f2bf(p - bf2f(hb));
      }
      *(bf16x8*)(ph_ + row * 72 + j0)     = h0;
      *(bf16x8*)(ph_ + row * 72 + j0 + 8) = h1;
      *(bf16x8*)(pl_ + row * 72 + j0)     = l0;
      *(bf16x8*)(pl_ + row * 72 + j0 + 8) = l1;
    }
    __syncthreads();

    // ---- PV (M=64,N=32,K=64) + store (fp32 path: packed {hi,lo} u32) ----
    {
      f32x4 oacc[2];
#pragma unroll
      for (int nc = 0; nc < 2; ++nc) oacc[nc] = (f32x4){0.f, 0.f, 0.f, 0.f};

#pragma unroll
      for (int ks = 0; ks < 2; ++ks) {
        const int kk = ks * 32 + l4 * 8;
        const int arow = wid * 16 + l15;
        bf16x8 Ap_h = *(const bf16x8*)(ph_ + arow * 72 + kk);
        bf16x8 Ap_l = *(const bf16x8*)(pl_ + arow * 72 + kk);
#pragma unroll
        for (int nc = 0; nc < 2; ++nc) {
          int bcol = nc * 16 + l15;
          bf16x8 Bv_h = *(const bf16x8*)(vth + bcol * 72 + kk);
          bf16x8 Bv_l = *(const bf16x8*)(vtl + bcol * 72 + kk);
          oacc[nc] = __builtin_amdgcn_mfma_f32_16x16x32_bf16(Ap_h, Bv_h, oacc[nc], 0, 0, 0);
          oacc[nc] = __builtin_amdgcn_mfma_f32_16x16x32_bf16(Ap_h, Bv_l, oacc[nc], 0, 0, 0);
          oacc[nc] = __builtin_amdgcn_mfma_f32_16x16x32_bf16(Ap_l, Bv_h, oacc[nc], 0, 0, 0);
        }
      }
#pragma unroll
      for (int nc = 0; nc < 2; ++nc) {
        int d = nc * 16 + l15;
#pragma unroll
        for (int r = 0; r < 4; ++r) {
          int row = wid * 16 + l4 * 4 + r;
          if (row < NTOK) {
            size_t idx = ((size_t)b * NTOK + row) * DIM + h * DH + d;
            float val = oacc[nc][r];
            if constexpr (sizeof(T) == 4) {
              unsigned short hb = f2bf(val);
              unsigned short lb = f2bf(val - bf2f(hb));
              ((unsigned int*)out)[idx] = ((unsigned int)hb << 16) | lb;
            } else {
              stf(out, idx, val);
            }
          }
        }
      }
    }
    __syncthreads();   // scratch safe for next head
  }
}

// ---------- MFMA in-place output projection ----------
// fp32 path: A read as packed {bf16hi,bf16lo} u32 (written by attn), final fp32 stored.
template <typename T>
__global__ __launch_bounds__(256, 2)
void proj_mfma_kernel(T* __restrict__ out, const unsigned short* __restrict__ wsb,
                      const T* __restrict__ proj_b, const int* __restrict__ flag, int want)
{
  if (*flag != want) return;
  constexpr int NS = (sizeof(T) == 4) ? 2 : 1;
  constexpr int SMEM_BYTES = NS * 256 * 72 * 2;
  __shared__ __align__(16) char smem[SMEM_BYTES];
  unsigned short* wh = (unsigned short*)smem;
  unsigned short* wl = wh + 256 * 72;

  const int tid = threadIdx.x;
  const int lane = tid & 63, wid = tid >> 6;
  const int wrow = (wid & 1) * 32, wcol = (wid >> 1) * 128;
  const int l15 = lane & 15, l4 = lane >> 4;
  const size_t r0 = (size_t)blockIdx.x * 64;
  const unsigned short* ph = wsb + OFF_PH;
  const unsigned short* pl = wsb + OFF_PL;

  f32x4 acc[2][8];
#pragma unroll
  for (int fi = 0; fi < 2; ++fi)
#pragma unroll
    for (int ni = 0; ni < 8; ++ni) acc[fi][ni] = (f32x4){0.f, 0.f, 0.f, 0.f};

  for (int kt = 0; kt < DIM; kt += 64) {
    for (int i = tid; i < 256 * 8; i += 256) {
      int j = i >> 3, k8 = (i & 7) * 8;
      *(int4*)(wh + j * 72 + k8) = *(const int4*)(ph + (size_t)j * DIM + kt + k8);
      if constexpr (NS == 2)
        *(int4*)(wl + j * 72 + k8) = *(const int4*)(pl + (size_t)j * DIM + kt + k8);
    }
    __syncthreads();

#pragma unroll
    for (int ks = 0; ks < 2; ++ks) {
      const int koff = kt + ks * 32 + l4 * 8;
      bf16x8 Ah[2], Al[2];
#pragma unroll
      for (int fi = 0; fi < 2; ++fi) {
        size_t row = r0 + wrow + fi * 16 + l15;
        if constexpr (NS == 2) {
          const unsigned int* yp = reinterpret_cast<const unsigned int*>(out) + row * DIM + koff;
          uint4 u0 = *(const uint4*)yp;
          uint4 u1 = *(const uint4*)(yp + 4);
          unsigned int uu[8] = {u0.x, u0.y, u0.z, u0.w, u1.x, u1.y, u1.z, u1.w};
#pragma unroll
          for (int t = 0; t < 8; ++t) {
            Ah[fi][t] = (short)(uu[t] >> 16);
            Al[fi][t] = (short)(uu[t] & 0xFFFFu);
          }
        } else {
          const unsigned short* yp = reinterpret_cast<const unsigned short*>(out) + row * DIM + koff;
          Ah[fi] = *(const bf16x8*)yp;
        }
      }
      const int kb = ks * 32 + l4 * 8;
#pragma unroll
      for (int ni = 0; ni < 8; ++ni) {
        int off = (wcol + ni * 16 + l15) * 72 + kb;
        bf16x8 Bhf = *(const bf16x8*)(wh + off);
#pragma unroll
        for (int fi = 0; fi < 2; ++fi)
          acc[fi][ni] = __builtin_amdgcn_mfma_f32_16x16x32_bf16(Ah[fi], Bhf, acc[fi][ni], 0, 0, 0);
        if constexpr (NS == 2) {
          bf16x8 Blf = *(const bf16x8*)(wl + off);
#pragma unroll
          for (int fi = 0; fi < 2; ++fi) {
            acc[fi][ni] = __builtin_amdgcn_mfma_f32_16x16x32_bf16(Ah[fi], Blf, acc[fi][ni], 0, 0, 0);
            acc[fi][ni] = __builtin_amdgcn_mfma_f32_16x16x32_bf16(Al[fi], Bhf, acc[fi][ni], 0, 0, 0);
          }
        }
      }
    }
    __syncthreads();
  }

#pragma unroll
  for (int fi = 0; fi < 2; ++fi) {
    size_t rbase = r0 + wrow + fi * 16 + l4 * 4;
#pragma unroll
    for (int ni = 0; ni < 8; ++ni) {
      int col = wcol + ni * 16 + l15;
      float bias = ldf(proj_b, (size_t)col);
#pragma unroll
      for (int r = 0; r < 4; ++r)
        stf(out, (rbase + r) * DIM + col, acc[fi][ni][r] + bias);
    }
  }
}

// ================= legacy fallback (ws too small for weight pre-split) =================
template <typename T>
__global__ __launch_bounds__(256, 2)
void win_attn_kernel(const T* __restrict__ x, const T* __restrict__ maskp,
                     const T* __restrict__ qkv_w, const T* __restrict__ qkv_b,
                     const T* __restrict__ rpb_table, const int* __restrict__ rel_index,
                     T* __restrict__ out, const int* __restrict__ flag, int want)
{
  if (*flag != want) return;

  const int b = blockIdx.x;
  const int h = blockIdx.y;
  const int tid = threadIdx.x;
  const int tx = tid & 15;
  const int ty = tid >> 4;

  __shared__ __align__(16) float xst[64][68];
  __shared__ __align__(16) float wt[96][68];
  __shared__ __align__(16) float qs[NTOK][36];
  __shared__ __align__(16) float ks2[NTOK][36];
  __shared__ __align__(16) float vs[NTOK][36];
  __shared__ __align__(16) float sm[NTOK][52];

  const float SCALE = 0.17677669529663687f;

  float acc[4][6];
#pragma unroll
  for (int i = 0; i < 4; ++i)
#pragma unroll
    for (int m = 0; m < 6; ++m) acc[i][m] = 0.0f;

  const size_t xbase = (size_t)b * NTOK * DIM;

  for (int kt = 0; kt < DIM; kt += 64) {
    for (int i = tid; i < NTOK * 64; i += 256) {
      int n = i >> 6, kk = i & 63;
      xst[n][kk] = ldf(x, xbase + (size_t)n * DIM + kt + kk);
    }
    for (int i = tid; i < 96 * 64; i += 256) {
      int j = i >> 6, kk = i & 63;
      int c = j >> 5, d = j & 31;
      wt[j][kk] = ldf(qkv_w, (size_t)(c * DIM + h * DH + d) * DIM + kt + kk);
    }
    __syncthreads();

#pragma unroll 2
    for (int kk = 0; kk < 64; kk += 4) {
      float4 av[4], bv[6];
#pragma unroll
      for (int i = 0; i < 4; ++i) av[i] = *(const float4*)&xst[ty + 16 * i][kk];
#pragma unroll
      for (int m = 0; m < 6; ++m) bv[m] = *(const float4*)&wt[tx + 16 * m][kk];
#pragma unroll
      for (int i = 0; i < 4; ++i)
#pragma unroll
        for (int m = 0; m < 6; ++m) {
          acc[i][m] += av[i].x * bv[m].x;
          acc[i][m] += av[i].y * bv[m].y;
          acc[i][m] += av[i].z * bv[m].z;
          acc[i][m] += av[i].w * bv[m].w;
        }
    }
    __syncthreads();
  }

#pragma unroll
  for (int i = 0; i < 4; ++i) {
    int n = ty + 16 * i;
    if (n < NTOK) {
#pragma unroll
      for (int m = 0; m < 6; ++m) {
        int j = tx + 16 * m;
        int c = j >> 5, d = j & 31;
        float v = acc[i][m] + ldf(qkv_b, c * DIM + h * DH + d);
        if (c == 0)      qs[n][d] = v * SCALE;
        else if (c == 1) ks2[n][d] = v;
        else             vs[n][d] = v;
      }
    }
  }
  __syncthreads();

  const int w = b & 63;
  for (int e = tid; e < NTOK * NTOK; e += 256) {
    int i = e / 49, j = e % 49;
    const float4* qi = (const float4*)qs[i];
    const float4* kj = (const float4*)ks2[j];
    float s = 0.0f;
#pragma unroll
    for (int d4 = 0; d4 < 8; ++d4) {
      float4 a = qi[d4], c = kj[d4];
      s += a.x * c.x + a.y * c.y + a.z * c.z + a.w * c.w;
    }
    s += ldf(rpb_table, (size_t)rel_index[e] * NH + h);
    s += ldf(maskp, (size_t)w * NTOK * NTOK + e);
    sm[i][j] = s;
  }
  __syncthreads();

  if (tid < NTOK) {
    int i = tid;
    float mx = -3.4e38f;
    for (int j = 0; j < NTOK; ++j) mx = fmaxf(mx, sm[i][j]);
    float sum = 0.0f;
    for (int j = 0; j < NTOK; ++j) {
      float ev = __expf(sm[i][j] - mx);
      sm[i][j] = ev;
      sum += ev;
    }
    float inv = 1.0f / sum;
    for (int j = 0; j < NTOK; ++j) sm[i][j] *= inv;
  }
  __syncthreads();

  for (int e = tid; e < NTOK * DH; e += 256) {
    int i = e >> 5, d = e & 31;
    float o = 0.0f;
    for (int j = 0; j < NTOK; ++j) o += sm[i][j] * vs[j][d];
    stf(out, ((size_t)b * NTOK + i) * DIM + h * DH + d, o);
  }
}

template <typename T>
__global__ __launch_bounds__(256, 2)
void proj_kernel(T* __restrict__ out, const T* __restrict__ proj_w,
                 const T* __restrict__ proj_b, const int* __restrict__ flag, int want)
{
  if (*flag != want) return;

  const int tid = threadIdx.x;
  const int tx = tid & 15;
  const int ty = tid >> 4;
  const size_t r0 = (size_t)blockIdx.x * 32;

  __shared__ __align__(16) float xs[32][260];
  __shared__ __align__(16) float pwt[256][36];

  for (int i = tid; i < 32 * 256; i += 256) {
    int n = i >> 8, c = i & 255;
    xs[n][c] = ldf((const T*)out, (r0 + n) * DIM + c);
  }
  __syncthreads();

  float acc[2][16];
#pragma unroll
  for (int i = 0; i < 2; ++i)
#pragma unroll
    for (int m = 0; m < 16; ++m) acc[i][m] = 0.0f;

  for (int kt = 0; kt < DIM; kt += 32) {
    for (int i = tid; i < 256 * 32; i += 256) {
      int j = i >> 5, kk = i & 31;
      pwt[j][kk] = ldf(proj_w, (size_t)j * DIM + kt + kk);
    }
    __syncthreads();

#pragma unroll 2
    for (int kk = 0; kk < 32; kk += 4) {
      float4 av[2], bv[16];
#pragma unroll
      for (int i = 0; i < 2; ++i) av[i] = *(const float4*)&xs[ty + 16 * i][kt + kk];
#pragma unroll
      for (int m = 0; m < 16; ++m) bv[m] = *(const float4*)&pwt[tx + 16 * m][kk];
#pragma unroll
      for (int i = 0; i < 2; ++i)
#pragma unroll
        for (int m = 0; m < 16; ++m) {
          acc[i][m] += av[i].x * bv[m].x;
          acc[i][m] += av[i].y * bv[m].y;
          acc[i][m] += av[i].z * bv[m].z;
          acc[i][m] += av[i].w * bv[m].w;
        }
    }
    __syncthreads();
  }

#pragma unroll
  for (int i = 0; i < 2; ++i) {
    int n = ty + 16 * i;
#pragma unroll
    for (int m = 0; m < 16; ++m) {
      int c = tx + 16 * m;
      stf(out, (r0 + n) * DIM + c, acc[i][m] + ldf(proj_b, c));
    }
  }
}

extern "C" void kernel_launch(void* const* d_in, const int* in_sizes, int n_in,
                              void* d_out, int out_size, void* d_ws, size_t ws_size,
                              hipStream_t stream) {
  const void* x      = d_in[0];
  const void* maskp  = d_in[1];
  const void* qkv_w  = d_in[2];
  const void* qkv_b  = d_in[3];
  const void* proj_w = d_in[4];
  const void* proj_b = d_in[5];
  const void* rpb    = d_in[6];
  const int*  rel    = (const int*)d_in[7];

  int* flag = (int*)d_ws;
  dtype_detect_kernel<<<dim3(1), dim3(64), 0, stream>>>((const unsigned int*)x, flag);

  const size_t WS_NEED = 16 + 1048576;
  if (ws_size >= WS_NEED) {
    unsigned short* wsb = (unsigned short*)((char*)d_ws + 16);

    prep_w_kernel<float><<<dim3(256), dim3(256), 0, stream>>>(
        (const float*)qkv_w, (const float*)proj_w, wsb, flag, 0);
    prep_w_kernel<__hip_bfloat16><<<dim3(256), dim3(256), 0, stream>>>(
        (const __hip_bfloat16*)qkv_w, (const __hip_bfloat16*)proj_w, wsb, flag, 1);

    dim3 gA(NB, 2);   // 4 heads per block
    win_attn_mfma_kernel<float><<<gA, 256, 0, stream>>>(
        (const float*)x, (const float*)maskp, (const float*)qkv_b,
        (const float*)rpb, rel, wsb, (float*)d_out, flag, 0);
    win_attn_mfma_kernel<__hip_bfloat16><<<gA, 256, 0, stream>>>(
        (const __hip_bfloat16*)x, (const __hip_bfloat16*)maskp, (const __hip_bfloat16*)qkv_b,
        (const __hip_bfloat16*)rpb, rel, wsb, (__hip_bfloat16*)d_out, flag, 1);

    proj_mfma_kernel<float><<<dim3(1568), 256, 0, stream>>>(
        (float*)d_out, wsb, (const float*)proj_b, flag, 0);
    proj_mfma_kernel<__hip_bfloat16><<<dim3(1568), 256, 0, stream>>>(
        (__hip_bfloat16*)d_out, wsb, (const __hip_bfloat16*)proj_b, flag, 1);
  } else {
    dim3 gA(NB, NH);
    win_attn_kernel<float><<<gA, 256, 0, stream>>>(
        (const float*)x, (const float*)maskp, (const float*)qkv_w, (const float*)qkv_b,
        (const float*)rpb, rel, (float*)d_out, flag, 0);
    win_attn_kernel<__hip_bfloat16><<<gA, 256, 0, stream>>>(
        (const __hip_bfloat16*)x, (const __hip_bfloat16*)maskp, (const __hip_bfloat16*)qkv_w,
        (const __hip_bfloat16*)qkv_b, (const __hip_bfloat16*)rpb, rel,
        (__hip_bfloat16*)d_out, flag, 1);

    dim3 gB(3136);
    proj_kernel<float><<<gB, 256, 0, stream>>>(
        (float*)d_out, (const float*)proj_w, (const float*)proj_b, flag, 0);
    proj_kernel<__hip_bfloat16><<<gB, 256, 0, stream>>>(
        (__hip_bfloat16*)d_out, (const __hip_bfloat16*)proj_w, (const __hip_bfloat16*)proj_b,
        flag, 1);
  }
}